// Round 22
// baseline (209.733 us; speedup 1.0000x reference)
//
#include <hip/hip_runtime.h>
#include <hip/hip_bf16.h>

typedef __attribute__((ext_vector_type(4))) float f32x4;
typedef __attribute__((ext_vector_type(8))) short bf16x8;

#define AS1 __attribute__((address_space(1)))
#define AS3 __attribute__((address_space(3)))

__device__ __forceinline__ void gload16(const void* g, void* l) {
    __builtin_amdgcn_global_load_lds((AS1 const void*)g, (AS3 void*)l, 16, 0, 0);
}

__device__ __forceinline__ unsigned short f2bf(float f) {
    union { float f; unsigned int u; } v; v.f = f;
    unsigned int u = v.u;
    unsigned int r = (u + 0x7FFFu + ((u >> 16) & 1u)) >> 16;
    return (unsigned short)r;
}

// gelu_tanh via sigmoid identity: 0.5*(1+tanh(u)) == 1/(1+e^{-2u})
__device__ __forceinline__ float gelu_t(float x) {
    float x3 = x * x * x;
    float e = -2.3022082299f * (x + 0.044715f * x3);
    return x / (1.0f + exp2f(e));
}

// ---------------------------------------------------------------------------
// 256xBN BK=64 GEMM. Fragment-read pipeline, no intra-tile barriers.
// BN = 256 (FFN1) or 192 (QKV -> 16x16 grid = 1 block/CU).
// ---------------------------------------------------------------------------
template<int EPI, int BN>
__global__ __launch_bounds__(512, 2) void gemm_bt256(
    const unsigned short* __restrict__ A,
    const unsigned short* __restrict__ Bt,
    void* __restrict__ C,
    const float* __restrict__ bias,
    int M, int N, int K)
{
    constexpr int NFR = (BN == 256) ? 4 : 3;      // B frags per wave
    __shared__ alignas(16) unsigned short As[2][2][128 * 64];
    __shared__ alignas(16) unsigned short Bs[2][BN * 64];
    const int t = threadIdx.x;
    const int lane = t & 63;
    const int w = t >> 6;
    const int wm = w >> 2, wn = w & 3;
    const int la = lane & 15, lg = lane >> 4;
    const int brow = blockIdx.x * 256, bcol = blockIdx.y * BN;
    const int xk = la & 7;

    const int sr = t >> 3;                    // 0..63
    const int sc = t & 7;                     // 16B chunk 0..7
    const int scs = (sc ^ (sr & 7)) * 8;      // pre-swizzled source col
    const unsigned short* aB = A + (size_t)(brow + sr) * K + scs;
    const unsigned short* bB = Bt + (size_t)(bcol + sr) * K + scs;
    const size_t g64 = (size_t)64 * K;
    const int ld0 = sr * 64 + sc * 8;

    f32x4 acc[8][NFR];
#pragma unroll
    for (int m = 0; m < 8; m++)
#pragma unroll
        for (int n = 0; n < NFR; n++)
            acc[m][n] = (f32x4){0.f, 0.f, 0.f, 0.f};

    const int nk = K >> 6;
    {   // prologue: tile 0 (order A0, B..., A1)
        unsigned short* d;
        d = &As[0][0][ld0]; gload16(aB, d);            gload16(aB + g64, d + 4096);
        if (BN == 256) {
            d = &Bs[0][ld0];        gload16(bB, d);            gload16(bB + g64, d + 4096);
            d = &Bs[0][8192 + ld0]; gload16(bB + 2 * g64, d);  gload16(bB + 3 * g64, d + 4096);
        } else {
#pragma unroll
            for (int s = 0; s < 3; s++)
                gload16(bB + s * g64, &Bs[0][s * 4096 + ld0]);
        }
        d = &As[0][1][ld0]; gload16(aB + 2 * g64, d);  gload16(aB + 3 * g64, d + 4096);
    }

    for (int kt = 0; kt < nk; ++kt) {
        const int cur = kt & 1, nxt = cur ^ 1;
        const bool hn = (kt + 1 < nk);
        const int k1 = (kt + 1) << 6;

        if (hn) {
            unsigned short* d = &As[nxt][0][ld0];
            gload16(aB + k1, d); gload16(aB + k1 + g64, d + 4096);
            asm volatile("s_waitcnt vmcnt(2)" ::: "memory");
        } else {
            asm volatile("s_waitcnt vmcnt(0)" ::: "memory");
        }
        __builtin_amdgcn_s_barrier();   // gate: tile kt staged everywhere

        const unsigned short* Ah = &As[cur][wm][0];
        const unsigned short* Bh = (BN == 256)
            ? &Bs[cur][(wn >> 1) * 8192] : &Bs[cur][0];
        const int br0 = (BN == 256) ? (wn & 1) * 64 : wn * 48;

        bf16x8 bfv[NFR], am[4];
        {   // phase-0 fragments (ks=0, mh=0)
            const int ch = (lg ^ xk) * 8;
#pragma unroll
            for (int n = 0; n < NFR; n++)
                bfv[n] = *(const bf16x8*)(Bh + (br0 + n * 16 + la) * 64 + ch);
#pragma unroll
            for (int mi = 0; mi < 4; mi++)
                am[mi] = *(const bf16x8*)(Ah + (mi * 16 + la) * 64 + ch);
        }

#pragma unroll
        for (int q = 0; q < 4; ++q) {
            const int mh = q & 1;
            bf16x8 amn[4], bfvn[NFR];
            if (q < 3) {   // prefetch next phase's fragments
                const int qn = q + 1, ksn = qn >> 1, mhn = qn & 1;
                const int chn = ((ksn * 4 + lg) ^ xk) * 8;
                if (mhn == 0) {
#pragma unroll
                    for (int n = 0; n < NFR; n++)
                        bfvn[n] = *(const bf16x8*)(Bh + (br0 + n * 16 + la) * 64 + chn);
                }
#pragma unroll
                for (int mi = 0; mi < 4; mi++)
                    amn[mi] = *(const bf16x8*)(Ah + ((mhn * 4 + mi) * 16 + la) * 64 + chn);
            }
            if (hn) {   // stage next K-tile halves (targets nxt: no hazard)
                if (BN == 256) {
                    unsigned short* d;
                    if (q == 0) {
                        d = &Bs[nxt][ld0];
                        gload16(bB + k1, d); gload16(bB + k1 + g64, d + 4096);
                    } else if (q == 1) {
                        d = &As[nxt][1][ld0];
                        gload16(aB + k1 + 2 * g64, d); gload16(aB + k1 + 3 * g64, d + 4096);
                    } else if (q == 2) {
                        d = &Bs[nxt][8192 + ld0];
                        gload16(bB + k1 + 2 * g64, d); gload16(bB + k1 + 3 * g64, d + 4096);
                    }
                } else {
                    if (q == 0) {
#pragma unroll
                        for (int s = 0; s < 3; s++)
                            gload16(bB + k1 + s * g64, &Bs[nxt][s * 4096 + ld0]);
                    } else if (q == 1) {
                        unsigned short* d = &As[nxt][1][ld0];
                        gload16(aB + k1 + 2 * g64, d); gload16(aB + k1 + 3 * g64, d + 4096);
                    }
                }
            }
            __builtin_amdgcn_s_setprio(1);
#pragma unroll
            for (int mi = 0; mi < 4; mi++) {
                const int m = mh * 4 + mi;
#pragma unroll
                for (int n = 0; n < NFR; n++)
                    acc[m][n] = __builtin_amdgcn_mfma_f32_16x16x32_bf16(
                        am[mi], bfv[n], acc[m][n], 0, 0, 0);
            }
            __builtin_amdgcn_s_setprio(0);
            if (q < 3) {
#pragma unroll
                for (int mi = 0; mi < 4; mi++) am[mi] = amn[mi];
                if (((q + 1) & 1) == 0) {
#pragma unroll
                    for (int n = 0; n < NFR; n++) bfv[n] = bfvn[n];
                }
            }
        }
        __builtin_amdgcn_s_barrier();   // end: reads of cur done before overwrite
    }

#pragma unroll
    for (int m = 0; m < 8; m++)
#pragma unroll
        for (int n = 0; n < NFR; n++)
#pragma unroll
            for (int j = 0; j < 4; j++) {
                int row = brow + wm * 128 + m * 16 + lg * 4 + j;
                int col = bcol + ((BN == 256) ? wn * 64 : wn * 48) + n * 16 + la;
                float v = acc[m][n][j];
                if (EPI == 0) {
                    ((unsigned short*)C)[(size_t)row * N + col] = f2bf(v);
                } else {
                    ((unsigned short*)C)[(size_t)row * N + col] =
                        f2bf(gelu_t(v + bias[col]));
                }
            }
}

// ---------------------------------------------------------------------------
// Split-K2 grouped GEMM (Wo, FFN2). 2 groups x 8 waves, 128x128, BK=64,
// 2 barriers per 32 MFMA, 1-round combine, T2 swizzle.
// ---------------------------------------------------------------------------
template<int EPI>
__global__ __launch_bounds__(1024) void gemm_bt_ks2(
    const unsigned short* __restrict__ A,
    const unsigned short* __restrict__ Bt,
    void* __restrict__ C,
    const float* __restrict__ bias,
    const float* __restrict__ res,
    int M, int N, int K)
{
    __shared__ alignas(16) char smem[131072];  // 2 grp x 2 buf x (A16K+B16K)
    const int t = threadIdx.x;
    const int g = t >> 9;           // K-half 0..1
    const int tl = t & 511;
    const int lane = t & 63;
    const int w = tl >> 6;          // 0..7
    const int wm = w >> 2, wn = w & 3;
    const int la = lane & 15, lg = lane >> 4;
    const int brow = blockIdx.x * 128, bcol = blockIdx.y * 128;
    const int wr = wm * 64, wc = wn * 32;
    const int xk = la & 7;

    const int Kg = K >> 1;
    const int kbase = g * Kg;

    const int sr = tl >> 3;         // 0..63
    const int sc = tl & 7;
    const int scs = (sc ^ (sr & 7)) * 8;
    const unsigned short* aB = A + (size_t)(brow + sr) * K + kbase + scs;
    const unsigned short* bB = Bt + (size_t)(bcol + sr) * K + kbase + scs;
    const size_t g64r = (size_t)64 * K;     // 64 rows down
    const int ld0 = sr * 64 + sc * 8;

    f32x4 acc[4][2];
#pragma unroll
    for (int m = 0; m < 4; m++)
#pragma unroll
        for (int n = 0; n < 2; n++)
            acc[m][n] = (f32x4){0.f, 0.f, 0.f, 0.f};

    const int nk = Kg >> 6;
    {   // prologue: A0, A1, B0, B1 of tile 0
        unsigned short* ab = (unsigned short*)(smem + g * 65536);
        gload16(aB, ab + ld0);
        gload16(aB + g64r, ab + 4096 + ld0);
        gload16(bB, ab + 8192 + ld0);
        gload16(bB + g64r, ab + 12288 + ld0);
    }

    for (int kt = 0; kt < nk; ++kt) {
        const int cur = kt & 1, nxt = cur ^ 1;
        const bool hn = (kt + 1 < nk);
        const int k1 = (kt + 1) << 6;
        unsigned short* nb = (unsigned short*)(smem + g * 65536 + nxt * 32768);

        if (hn) {   // issue next A pair, wait current 4
            gload16(aB + k1, nb + ld0);
            gload16(aB + k1 + g64r, nb + 4096 + ld0);
            asm volatile("s_waitcnt vmcnt(2)" ::: "memory");
        } else {
            asm volatile("s_waitcnt vmcnt(0)" ::: "memory");
        }
        __builtin_amdgcn_s_barrier();

        const unsigned short* Asg =
            (const unsigned short*)(smem + g * 65536 + cur * 32768);
        const unsigned short* Bsg = Asg + 8192;

        // phase ks=0
        {
            const int ch = (lg ^ xk) * 8;
            bf16x8 af[4], bfv[2];
#pragma unroll
            for (int m = 0; m < 4; m++)
                af[m] = *(const bf16x8*)(Asg + (wr + m * 16 + la) * 64 + ch);
#pragma unroll
            for (int n = 0; n < 2; n++)
                bfv[n] = *(const bf16x8*)(Bsg + (wc + n * 16 + la) * 64 + ch);
            if (hn) {   // issue next B pair (targets nxt buffer: no hazard)
                gload16(bB + k1, nb + 8192 + ld0);
                gload16(bB + k1 + g64r, nb + 12288 + ld0);
            }
            __builtin_amdgcn_s_setprio(1);
#pragma unroll
            for (int m = 0; m < 4; m++)
#pragma unroll
                for (int n = 0; n < 2; n++)
                    acc[m][n] = __builtin_amdgcn_mfma_f32_16x16x32_bf16(
                        af[m], bfv[n], acc[m][n], 0, 0, 0);
            __builtin_amdgcn_s_setprio(0);
        }
        // phase ks=1 (no barrier: reads cur, writes went to nxt)
        {
            const int ch = ((4 | lg) ^ xk) * 8;
            bf16x8 af[4], bfv[2];
#pragma unroll
            for (int m = 0; m < 4; m++)
                af[m] = *(const bf16x8*)(Asg + (wr + m * 16 + la) * 64 + ch);
#pragma unroll
            for (int n = 0; n < 2; n++)
                bfv[n] = *(const bf16x8*)(Bsg + (wc + n * 16 + la) * 64 + ch);
            __builtin_amdgcn_s_setprio(1);
#pragma unroll
            for (int m = 0; m < 4; m++)
#pragma unroll
                for (int n = 0; n < 2; n++)
                    acc[m][n] = __builtin_amdgcn_mfma_f32_16x16x32_bf16(
                        af[m], bfv[n], acc[m][n], 0, 0, 0);
            __builtin_amdgcn_s_setprio(0);
        }
        __builtin_amdgcn_s_barrier();   // reads of cur done before overwrite
    }

    // ---- single-round combine: group 1 -> group 0 ----
    float* cbuf = (float*)smem;
    __syncthreads();
    if (g == 1) {
#pragma unroll
        for (int m = 0; m < 4; m++)
#pragma unroll
            for (int n = 0; n < 2; n++)
#pragma unroll
                for (int j = 0; j < 4; j++)
                    cbuf[(wr + m * 16 + lg * 4 + j) * 132 + wc + n * 16 + la] =
                        acc[m][n][j];
    }
    __syncthreads();
    if (g != 0) return;

#pragma unroll
    for (int m = 0; m < 4; m++)
#pragma unroll
        for (int n = 0; n < 2; n++)
#pragma unroll
            for (int j = 0; j < 4; j++) {
                int row = brow + wr + m * 16 + lg * 4 + j;
                int col = bcol + wc + n * 16 + la;
                float v = acc[m][n][j] +
                          cbuf[(wr + m * 16 + lg * 4 + j) * 132 + wc + n * 16 + la];
                if (EPI == 0) {
                    ((unsigned short*)C)[(size_t)row * N + col] = f2bf(v);
                } else if (EPI == 1) {
                    ((float*)C)[(size_t)row * N + col] =
                        v + bias[col] + res[(size_t)row * N + col];
                } else {
                    ((unsigned short*)C)[(size_t)row * N + col] =
                        f2bf(gelu_t(v + bias[col]));
                }
            }
}

// ---------------------------------------------------------------------------
// Causal flash attention, QBLK=128: 8 waves x 16 q-rows (NO group split, NO
// merge). KV tiles of 64 double-buffered (16KB/buf) with counted vmcnt(2)
// gate; block processes qt-pair {r, 15-r} serially (34 tiles, uniform);
// cross-half prefetch keeps the pipeline full. NO-MAX softmax (bounded
// scores), swapped QK^T in-register softmax, Ps stride 64 swizzled.
// Grid 256 = 1 block/CU. LDS 48KB.
// ---------------------------------------------------------------------------
__global__ __launch_bounds__(512) void attn_kernel(
    const unsigned short* __restrict__ QKV,
    const unsigned short* __restrict__ Vt,
    unsigned short* __restrict__ ctx)
{
    __shared__ alignas(16) unsigned short KVs[2][8192];   // [buf] K(8KB)|V(8KB)
    __shared__ alignas(16) unsigned short Ps[8][16 * 64]; // 16KB

    const int t = threadIdx.x, lane = t & 63, w = t >> 6;
    const int la = lane & 15, lg = lane >> 4;
    const int id = blockIdx.x;
    const int c = id & 31;
    const int h = c >> 1, b = c & 1;
    const int r = id >> 5;                  // 0..7
    const float C2 = 0.18033688011112042f; // 0.125 * log2(e)

    const unsigned short* kg = QKV + (size_t)(b * 2048) * 3072 + 1024 + h * 64;
    const unsigned short* vg = Vt + (size_t)((b * 16 + h) * 64) * 2048;
    const int sr = t >> 3;                  // 0..63
    const int sc = t & 7;
    const int sxcol = ((sc ^ (sr & 7)) * 8);

    unsigned short* pw = (unsigned short*)Ps[w];
    const int xk = la & 7;

    int cur = 0;
    {   // prologue: stage tile 0 of half 0 (qt = r) into buf 0
        unsigned short* kd = KVs[0];
        gload16(kg + (size_t)sr * 3072 + sxcol, kd + t * 8);
        gload16(vg + (size_t)sr * 2048 + sxcol, kd + 4096 + t * 8);
    }

    for (int half = 0; half < 2; ++half) {
        const int qt = half ? (15 - r) : r;
        const int qbase = qt * 128;
        const int qr = qbase + w * 16 + la;
        const int nt = 2 * qt + 2;
        const int qtn = 15 - r;             // next half's qt (only used half==0)

        const unsigned short* qp =
            QKV + (size_t)(b * 2048 + qbase + w * 16 + la) * 3072 + h * 64;
        bf16x8 qf0 = *(const bf16x8*)(qp + lg * 8);
        bf16x8 qf1 = *(const bf16x8*)(qp + 32 + lg * 8);

        f32x4 o[4];
#pragma unroll
        for (int n = 0; n < 4; n++) o[n] = (f32x4){0.f, 0.f, 0.f, 0.f};
        float lrow = 0.f;

        for (int tile = 0; tile < nt; ++tile) {
            const int nxt = cur ^ 1;
            const bool hn = (tile + 1 < nt) || (half == 0);
            if (hn) {   // stage next tile (or next half's tile 0) into nxt
                const int kv1 = (tile + 1 < nt) ? (tile + 1) * 64 : 0;
                unsigned short* kd = KVs[nxt];
                gload16(kg + (size_t)(kv1 + sr) * 3072 + sxcol, kd + t * 8);
                gload16(vg + (size_t)sr * 2048 + kv1 + sxcol, kd + 4096 + t * 8);
                asm volatile("s_waitcnt vmcnt(2)" ::: "memory");
            } else {
                asm volatile("s_waitcnt vmcnt(0)" ::: "memory");
            }
            __builtin_amdgcn_s_barrier();   // gate: tile staged everywhere

            const int kv = tile * 64;
            const unsigned short* Kc = KVs[cur];
            const unsigned short* Vc = Kc + 4096;

            f32x4 sa[4];
            __builtin_amdgcn_s_setprio(1);
#pragma unroll
            for (int n = 0; n < 4; n++) {
                f32x4 z = (f32x4){0.f, 0.f, 0.f, 0.f};
                const unsigned short* kr = Kc + (n * 16 + la) * 64;
                bf16x8 k0 = *(const bf16x8*)(kr + (lg ^ xk) * 8);
                bf16x8 k1 = *(const bf16x8*)(kr + ((4 | lg) ^ xk) * 8);
                z = __builtin_amdgcn_mfma_f32_16x16x32_bf16(k0, qf0, z, 0, 0, 0);
                z = __builtin_amdgcn_mfma_f32_16x16x32_bf16(k1, qf1, z, 0, 0, 0);
                sa[n] = z;
            }
            __builtin_amdgcn_s_setprio(0);
            if (tile >= 2 * qt) {   // last two tiles: causal mask
#pragma unroll
                for (int n = 0; n < 4; n++)
#pragma unroll
                    for (int jj = 0; jj < 4; jj++) {
                        int kc = kv + n * 16 + lg * 4 + jj;
                        if (kc > qr) sa[n][jj] = -1e30f;
                    }
            }
            // no-max softmax: exp2, pack+write P early, then reduce
#pragma unroll
            for (int n = 0; n < 4; n++)
#pragma unroll
                for (int jj = 0; jj < 4; jj++)
                    sa[n][jj] = exp2f(sa[n][jj] * C2);
#pragma unroll
            for (int n = 0; n < 4; n++)
#pragma unroll
                for (int jp = 0; jp < 2; jp++) {
                    unsigned int pk;
                    asm("v_cvt_pk_bf16_f32 %0, %1, %2"
                        : "=v"(pk) : "v"(sa[n][2 * jp]), "v"(sa[n][2 * jp + 1]));
                    int col = 16 * n + lg * 4 + 2 * jp;
                    int idx = la * 64 + (((col >> 3) ^ xk) * 8) + (col & 7);
                    *(unsigned int*)(pw + idx) = pk;
                }
            float psum = 0.f;
#pragma unroll
            for (int n = 0; n < 4; n++)
#pragma unroll
                for (int jj = 0; jj < 4; jj++)
                    psum += sa[n][jj];
            psum += __shfl_xor(psum, 16, 64);
            psum += __shfl_xor(psum, 32, 64);
            lrow += psum;
            asm volatile("s_waitcnt lgkmcnt(0)" ::: "memory");
            __builtin_amdgcn_s_setprio(1);
#pragma unroll
            for (int kk = 0; kk < 2; kk++) {
                bf16x8 pa = *(const bf16x8*)(pw + la * 64 + (((kk * 4 + lg) ^ xk) * 8));
#pragma unroll
                for (int n = 0; n < 4; n++) {
                    bf16x8 vb = *(const bf16x8*)(
                        Vc + (n * 16 + la) * 64 + (((kk * 4 + lg) ^ xk) * 8));
                    o[n] = __builtin_amdgcn_mfma_f32_16x16x32_bf16(pa, vb, o[n], 0, 0, 0);
                }
            }
            __builtin_amdgcn_s_setprio(0);
            __builtin_amdgcn_s_barrier();   // reads of cur done before overwrite
            cur ^= 1;
        }

        // ---- epilogue: registers + shfl only (no merge, no LDS) ----
        float linv = 1.0f / lrow;
        float invv[4];
#pragma unroll
        for (int jj = 0; jj < 4; jj++)
            invv[jj] = __shfl(linv, lg * 4 + jj, 64);
#pragma unroll
        for (int n = 0; n < 4; n++)
#pragma unroll
            for (int jj = 0; jj < 4; jj++) {
                int row = b * 2048 + qbase + w * 16 + lg * 4 + jj;
                int col = h * 64 + n * 16 + la;
                ctx[(size_t)row * 1024 + col] = f2bf(o[n][jj] * invv[jj]);
            }
        (void)qtn;
    }
}

// ---------------------------------------------------------------------------
__global__ __launch_bounds__(256) void ln_kernel(
    const float* __restrict__ x, const float* __restrict__ scale,
    const float* __restrict__ shift, unsigned short* __restrict__ out)
{
    const int row = blockIdx.x, t = threadIdx.x;
    const int lane = t & 63, w = t >> 6;
    const float4 v = ((const float4*)(x + (size_t)row * 1024))[t];
    float s = v.x + v.y + v.z + v.w;
#pragma unroll
    for (int off = 1; off < 64; off <<= 1) s += __shfl_xor(s, off, 64);
    __shared__ float red[8];
    if (lane == 0) red[w] = s;
    __syncthreads();
    float mean = (red[0] + red[1] + red[2] + red[3]) * (1.0f / 1024.0f);
    float d0 = v.x - mean, d1 = v.y - mean, d2 = v.z - mean, d3 = v.w - mean;
    float q = d0 * d0 + d1 * d1 + d2 * d2 + d3 * d3;
#pragma unroll
    for (int off = 1; off < 64; off <<= 1) q += __shfl_xor(q, off, 64);
    if (lane == 0) red[4 + w] = q;
    __syncthreads();
    float var = (red[4] + red[5] + red[6] + red[7]) * (1.0f / 1023.0f);
    float rinv = rsqrtf(var + 1e-6f);
    const int c = t * 4;
    out[(size_t)row * 1024 + c + 0] = f2bf(scale[c + 0] * (d0 * rinv) + shift[c + 0]);
    out[(size_t)row * 1024 + c + 1] = f2bf(scale[c + 1] * (d1 * rinv) + shift[c + 1]);
    out[(size_t)row * 1024 + c + 2] = f2bf(scale[c + 2] * (d2 * rinv) + shift[c + 2]);
    out[(size_t)row * 1024 + c + 3] = f2bf(scale[c + 3] * (d3 * rinv) + shift[c + 3]);
}

// ---------------------------------------------------------------------------
// Fused weight transpose: all 6 W[K][N] f32 -> Wt[N][K] bf16 in ONE launch.
// ---------------------------------------------------------------------------
__global__ __launch_bounds__(256) void transpose_all(
    const float* __restrict__ Wq, const float* __restrict__ Wk,
    const float* __restrict__ Wv, const float* __restrict__ Wo,
    const float* __restrict__ W1, const float* __restrict__ W2,
    unsigned short* __restrict__ WqkvT, unsigned short* __restrict__ WoT,
    unsigned short* __restrict__ W1T, unsigned short* __restrict__ W2T)
{
    __shared__ float tile[32][33];
    const int id = blockIdx.x;
    const float* W;
    unsigned short* Wt;
    int K, N, nb, kb;
    if (id < 4096) {
        const int wsel = id >> 10, loc = id & 1023;
        K = 1024; N = 1024;
        nb = (loc & 31) * 32; kb = (loc >> 5) * 32;
        W = (wsel == 0) ? Wq : (wsel == 1) ? Wk : (wsel == 2) ? Wv : Wo;
        Wt = (wsel == 3) ? WoT : (WqkvT + (size_t)wsel * 1024 * 1024);
    } else if (id < 8192) {
        const int loc = id - 4096;
        K = 1024; N = 4096;
        nb = (loc & 127) * 32; kb = (loc >> 7) * 32;
        W = W1; Wt = W1T;
    } else {
        const int loc = id - 8192;
        K = 4096; N = 1024;
        nb = (loc & 31) * 32; kb = (loc >> 5) * 32;
        W = W2; Wt = W2T;
    }
    const int tx = threadIdx.x, ty = threadIdx.y;
#pragma unroll
    for (int j = 0; j < 4; j++)
        tile[ty + j * 8][tx] = W[(size_t)(kb + ty + j * 8) * N + nb + tx];
    __syncthreads();
#pragma unroll
    for (int j = 0; j < 4; j++)
        Wt[(size_t)(nb + ty + j * 8) * K + kb + tx] = f2bf(tile[tx][ty + j * 8]);
}

// ---------------------------------------------------------------------------
__global__ __launch_bounds__(256) void transpose_v(
    const unsigned short* __restrict__ QKV, unsigned short* __restrict__ Vt)
{
    __shared__ unsigned short tile[32][33];
    const int sb = blockIdx.x * 32, hb = blockIdx.y * 32;
    const int bh = blockIdx.z;
    const int b = bh >> 4, h = bh & 15;
    const int tx = threadIdx.x, ty = threadIdx.y;
    const unsigned short* src = QKV + (size_t)(b * 2048) * 3072 + 2048 + h * 64;
#pragma unroll
    for (int j = 0; j < 4; j++)
        tile[ty + j * 8][tx] = src[(size_t)(sb + ty + j * 8) * 3072 + hb + tx];
    __syncthreads();
    unsigned short* dst = Vt + (size_t)((b * 16 + h) * 64) * 2048;
#pragma unroll
    for (int j = 0; j < 4; j++)
        dst[(size_t)(hb + ty + j * 8) * 2048 + sb + tx] = tile[tx][ty + j * 8];
}

// ---------------------------------------------------------------------------
extern "C" void kernel_launch(void* const* d_in, const int* in_sizes, int n_in,
                              void* d_out, int out_size, void* d_ws, size_t ws_size,
                              hipStream_t stream)
{
    const float* x      = (const float*)d_in[0];
    const float* Wq     = (const float*)d_in[1];
    const float* Wk     = (const float*)d_in[2];
    const float* Wv     = (const float*)d_in[3];
    const float* Wo     = (const float*)d_in[4];
    const float* bo     = (const float*)d_in[5];
    const float* W1     = (const float*)d_in[6];
    const float* b1     = (const float*)d_in[7];
    const float* W2     = (const float*)d_in[8];
    const float* b2     = (const float*)d_in[9];
    const float* scale1 = (const float*)d_in[10];
    const float* shift1 = (const float*)d_in[11];
    const float* scale2 = (const float*)d_in[12];
    const float* shift2 = (const float*)d_in[13];
    float* out = (float*)d_out;

    char* ws = (char*)d_ws;
    unsigned short* xn    = (unsigned short*)(ws);                   // 8MB (also yn)
    unsigned short* QKV   = (unsigned short*)(ws + (8ull << 20));    // 24MB
    unsigned short* VtB   = (unsigned short*)(ws + (32ull << 20));   // 8MB
    unsigned short* ctx   = (unsigned short*)(ws + (40ull << 20));   // 8MB
    unsigned short* g     = (unsigned short*)(ws + (8ull << 20));    // 32MB (reuse QKV+Vt)
    unsigned short* WqkvT = (unsigned short*)(ws + (48ull << 20));   // 6MB
    unsigned short* WoT   = (unsigned short*)(ws + (54ull << 20));   // 2MB
    unsigned short* W1T   = (unsigned short*)(ws + (56ull << 20));   // 8MB
    unsigned short* W2T   = (unsigned short*)(ws + (64ull << 20));   // 8MB -> 72MB total
    float* h = out;  // h lives in d_out

    dim3 blk(256);
    dim3 tb(32, 8);

    transpose_all<<<dim3(12288), tb, 0, stream>>>(Wq, Wk, Wv, Wo, W1, W2,
                                                  WqkvT, WoT, W1T, W2T);

    ln_kernel<<<4096, blk, 0, stream>>>(x, scale1, shift1, xn);
    gemm_bt256<0, 192><<<dim3(16, 16), dim3(512), 0, stream>>>(
        xn, WqkvT, QKV, nullptr, 4096, 3072, 1024);
    transpose_v<<<dim3(64, 2, 32), tb, 0, stream>>>(QKV, VtB);
    // QBLK=128, qt-pair serial, dbuf: 256 blocks = 1/CU
    attn_kernel<<<dim3(256), dim3(512), 0, stream>>>(QKV, VtB, ctx);
    gemm_bt_ks2<1><<<dim3(32, 8), dim3(1024), 0, stream>>>(ctx, WoT, h, bo, x,
                                                           4096, 1024, 1024);
    ln_kernel<<<4096, blk, 0, stream>>>(h, scale2, shift2, xn);
    gemm_bt256<2, 256><<<dim3(16, 16), dim3(512), 0, stream>>>(
        xn, W1T, g, b1, 4096, 4096, 1024);
    gemm_bt_ks2<1><<<dim3(32, 8), dim3(1024), 0, stream>>>(g, W2T, out, b2, h,
                                                           4096, 1024, 4096);
}

// Round 23
// 204.974 us; speedup vs baseline: 1.0232x; 1.0232x over previous
//
#include <hip/hip_runtime.h>
#include <hip/hip_bf16.h>

typedef __attribute__((ext_vector_type(4))) float f32x4;
typedef __attribute__((ext_vector_type(8))) short bf16x8;

#define AS1 __attribute__((address_space(1)))
#define AS3 __attribute__((address_space(3)))

__device__ __forceinline__ void gload16(const void* g, void* l) {
    __builtin_amdgcn_global_load_lds((AS1 const void*)g, (AS3 void*)l, 16, 0, 0);
}

__device__ __forceinline__ unsigned short f2bf(float f) {
    union { float f; unsigned int u; } v; v.f = f;
    unsigned int u = v.u;
    unsigned int r = (u + 0x7FFFu + ((u >> 16) & 1u)) >> 16;
    return (unsigned short)r;
}

// gelu_tanh via sigmoid identity: 0.5*(1+tanh(u)) == 1/(1+e^{-2u})
__device__ __forceinline__ float gelu_t(float x) {
    float x3 = x * x * x;
    float e = -2.3022082299f * (x + 0.044715f * x3);
    return x / (1.0f + exp2f(e));
}

// ---------------------------------------------------------------------------
// 256xBN BK=64 GEMM. Fragment-read pipeline, NO intra-tile barriers: all
// staging targets buf[nxt], all reads from buf[cur] -> only the two
// tile-boundary barriers are needed (gate vmcnt(2)+barrier, end barrier).
// BN = 256 (FFN1) or 192 (QKV -> 16x16 grid = 1 block/CU).
// ---------------------------------------------------------------------------
template<int EPI, int BN>
__global__ __launch_bounds__(512, 2) void gemm_bt256(
    const unsigned short* __restrict__ A,
    const unsigned short* __restrict__ Bt,
    void* __restrict__ C,
    const float* __restrict__ bias,
    int M, int N, int K)
{
    constexpr int NFR = (BN == 256) ? 4 : 3;      // B frags per wave
    __shared__ alignas(16) unsigned short As[2][2][128 * 64];
    __shared__ alignas(16) unsigned short Bs[2][BN * 64];
    const int t = threadIdx.x;
    const int lane = t & 63;
    const int w = t >> 6;
    const int wm = w >> 2, wn = w & 3;
    const int la = lane & 15, lg = lane >> 4;
    const int brow = blockIdx.x * 256, bcol = blockIdx.y * BN;
    const int xk = la & 7;

    const int sr = t >> 3;                    // 0..63
    const int sc = t & 7;                     // 16B chunk 0..7
    const int scs = (sc ^ (sr & 7)) * 8;      // pre-swizzled source col
    const unsigned short* aB = A + (size_t)(brow + sr) * K + scs;
    const unsigned short* bB = Bt + (size_t)(bcol + sr) * K + scs;
    const size_t g64 = (size_t)64 * K;
    const int ld0 = sr * 64 + sc * 8;

    f32x4 acc[8][NFR];
#pragma unroll
    for (int m = 0; m < 8; m++)
#pragma unroll
        for (int n = 0; n < NFR; n++)
            acc[m][n] = (f32x4){0.f, 0.f, 0.f, 0.f};

    const int nk = K >> 6;
    {   // prologue: tile 0 (order A0, B..., A1)
        unsigned short* d;
        d = &As[0][0][ld0]; gload16(aB, d);            gload16(aB + g64, d + 4096);
        if (BN == 256) {
            d = &Bs[0][ld0];        gload16(bB, d);            gload16(bB + g64, d + 4096);
            d = &Bs[0][8192 + ld0]; gload16(bB + 2 * g64, d);  gload16(bB + 3 * g64, d + 4096);
        } else {
#pragma unroll
            for (int s = 0; s < 3; s++)
                gload16(bB + s * g64, &Bs[0][s * 4096 + ld0]);
        }
        d = &As[0][1][ld0]; gload16(aB + 2 * g64, d);  gload16(aB + 3 * g64, d + 4096);
    }

    for (int kt = 0; kt < nk; ++kt) {
        const int cur = kt & 1, nxt = cur ^ 1;
        const bool hn = (kt + 1 < nk);
        const int k1 = (kt + 1) << 6;

        if (hn) {
            unsigned short* d = &As[nxt][0][ld0];
            gload16(aB + k1, d); gload16(aB + k1 + g64, d + 4096);
            asm volatile("s_waitcnt vmcnt(2)" ::: "memory");
        } else {
            asm volatile("s_waitcnt vmcnt(0)" ::: "memory");
        }
        __builtin_amdgcn_s_barrier();   // gate: tile kt staged everywhere

        const unsigned short* Ah = &As[cur][wm][0];
        const unsigned short* Bh = (BN == 256)
            ? &Bs[cur][(wn >> 1) * 8192] : &Bs[cur][0];
        const int br0 = (BN == 256) ? (wn & 1) * 64 : wn * 48;

        bf16x8 bfv[NFR], am[4];
        {   // phase-0 fragments (ks=0, mh=0)
            const int ch = (lg ^ xk) * 8;
#pragma unroll
            for (int n = 0; n < NFR; n++)
                bfv[n] = *(const bf16x8*)(Bh + (br0 + n * 16 + la) * 64 + ch);
#pragma unroll
            for (int mi = 0; mi < 4; mi++)
                am[mi] = *(const bf16x8*)(Ah + (mi * 16 + la) * 64 + ch);
        }

#pragma unroll
        for (int q = 0; q < 4; ++q) {
            const int mh = q & 1;
            bf16x8 amn[4], bfvn[NFR];
            if (q < 3) {   // prefetch next phase's fragments
                const int qn = q + 1, ksn = qn >> 1, mhn = qn & 1;
                const int chn = ((ksn * 4 + lg) ^ xk) * 8;
                if (mhn == 0) {
#pragma unroll
                    for (int n = 0; n < NFR; n++)
                        bfvn[n] = *(const bf16x8*)(Bh + (br0 + n * 16 + la) * 64 + chn);
                }
#pragma unroll
                for (int mi = 0; mi < 4; mi++)
                    amn[mi] = *(const bf16x8*)(Ah + ((mhn * 4 + mi) * 16 + la) * 64 + chn);
            }
            if (hn) {   // stage next K-tile halves (targets nxt: no hazard)
                if (BN == 256) {
                    unsigned short* d;
                    if (q == 0) {
                        d = &Bs[nxt][ld0];
                        gload16(bB + k1, d); gload16(bB + k1 + g64, d + 4096);
                    } else if (q == 1) {
                        d = &As[nxt][1][ld0];
                        gload16(aB + k1 + 2 * g64, d); gload16(aB + k1 + 3 * g64, d + 4096);
                    } else if (q == 2) {
                        d = &Bs[nxt][8192 + ld0];
                        gload16(bB + k1 + 2 * g64, d); gload16(bB + k1 + 3 * g64, d + 4096);
                    }
                } else {
                    if (q == 0) {
#pragma unroll
                        for (int s = 0; s < 3; s++)
                            gload16(bB + k1 + s * g64, &Bs[nxt][s * 4096 + ld0]);
                    } else if (q == 1) {
                        unsigned short* d = &As[nxt][1][ld0];
                        gload16(aB + k1 + 2 * g64, d); gload16(aB + k1 + 3 * g64, d + 4096);
                    }
                }
            }
            // NO phase barrier (writes->nxt, reads->cur: no hazard)
            __builtin_amdgcn_s_setprio(1);
#pragma unroll
            for (int mi = 0; mi < 4; mi++) {
                const int m = mh * 4 + mi;
#pragma unroll
                for (int n = 0; n < NFR; n++)
                    acc[m][n] = __builtin_amdgcn_mfma_f32_16x16x32_bf16(
                        am[mi], bfv[n], acc[m][n], 0, 0, 0);
            }
            __builtin_amdgcn_s_setprio(0);
            if (q < 3) {
#pragma unroll
                for (int mi = 0; mi < 4; mi++) am[mi] = amn[mi];
                if (((q + 1) & 1) == 0) {
#pragma unroll
                    for (int n = 0; n < NFR; n++) bfv[n] = bfvn[n];
                }
            }
        }
        __builtin_amdgcn_s_barrier();   // end: reads of cur done before overwrite
    }

#pragma unroll
    for (int m = 0; m < 8; m++)
#pragma unroll
        for (int n = 0; n < NFR; n++)
#pragma unroll
            for (int j = 0; j < 4; j++) {
                int row = brow + wm * 128 + m * 16 + lg * 4 + j;
                int col = bcol + ((BN == 256) ? wn * 64 : wn * 48) + n * 16 + la;
                float v = acc[m][n][j];
                if (EPI == 0) {
                    ((unsigned short*)C)[(size_t)row * N + col] = f2bf(v);
                } else {
                    ((unsigned short*)C)[(size_t)row * N + col] =
                        f2bf(gelu_t(v + bias[col]));
                }
            }
}

// ---------------------------------------------------------------------------
// Split-K2 grouped GEMM (Wo, FFN2). 2 groups x 8 waves, 128x128, BK=64,
// 2 barriers per 32 MFMA, 1-round combine, T2 swizzle.
// ---------------------------------------------------------------------------
template<int EPI>
__global__ __launch_bounds__(1024) void gemm_bt_ks2(
    const unsigned short* __restrict__ A,
    const unsigned short* __restrict__ Bt,
    void* __restrict__ C,
    const float* __restrict__ bias,
    const float* __restrict__ res,
    int M, int N, int K)
{
    __shared__ alignas(16) char smem[131072];  // 2 grp x 2 buf x (A16K+B16K)
    const int t = threadIdx.x;
    const int g = t >> 9;           // K-half 0..1
    const int tl = t & 511;
    const int lane = t & 63;
    const int w = tl >> 6;          // 0..7
    const int wm = w >> 2, wn = w & 3;
    const int la = lane & 15, lg = lane >> 4;
    const int brow = blockIdx.x * 128, bcol = blockIdx.y * 128;
    const int wr = wm * 64, wc = wn * 32;
    const int xk = la & 7;

    const int Kg = K >> 1;
    const int kbase = g * Kg;

    const int sr = tl >> 3;         // 0..63
    const int sc = tl & 7;
    const int scs = (sc ^ (sr & 7)) * 8;
    const unsigned short* aB = A + (size_t)(brow + sr) * K + kbase + scs;
    const unsigned short* bB = Bt + (size_t)(bcol + sr) * K + kbase + scs;
    const size_t g64r = (size_t)64 * K;     // 64 rows down
    const int ld0 = sr * 64 + sc * 8;

    f32x4 acc[4][2];
#pragma unroll
    for (int m = 0; m < 4; m++)
#pragma unroll
        for (int n = 0; n < 2; n++)
            acc[m][n] = (f32x4){0.f, 0.f, 0.f, 0.f};

    const int nk = Kg >> 6;
    {   // prologue: A0, A1, B0, B1 of tile 0
        unsigned short* ab = (unsigned short*)(smem + g * 65536);
        gload16(aB, ab + ld0);
        gload16(aB + g64r, ab + 4096 + ld0);
        gload16(bB, ab + 8192 + ld0);
        gload16(bB + g64r, ab + 12288 + ld0);
    }

    for (int kt = 0; kt < nk; ++kt) {
        const int cur = kt & 1, nxt = cur ^ 1;
        const bool hn = (kt + 1 < nk);
        const int k1 = (kt + 1) << 6;
        unsigned short* nb = (unsigned short*)(smem + g * 65536 + nxt * 32768);

        if (hn) {   // issue next A pair, wait current 4
            gload16(aB + k1, nb + ld0);
            gload16(aB + k1 + g64r, nb + 4096 + ld0);
            asm volatile("s_waitcnt vmcnt(2)" ::: "memory");
        } else {
            asm volatile("s_waitcnt vmcnt(0)" ::: "memory");
        }
        __builtin_amdgcn_s_barrier();

        const unsigned short* Asg =
            (const unsigned short*)(smem + g * 65536 + cur * 32768);
        const unsigned short* Bsg = Asg + 8192;

        // phase ks=0
        {
            const int ch = (lg ^ xk) * 8;
            bf16x8 af[4], bfv[2];
#pragma unroll
            for (int m = 0; m < 4; m++)
                af[m] = *(const bf16x8*)(Asg + (wr + m * 16 + la) * 64 + ch);
#pragma unroll
            for (int n = 0; n < 2; n++)
                bfv[n] = *(const bf16x8*)(Bsg + (wc + n * 16 + la) * 64 + ch);
            if (hn) {   // issue next B pair (targets nxt buffer: no hazard)
                gload16(bB + k1, nb + 8192 + ld0);
                gload16(bB + k1 + g64r, nb + 12288 + ld0);
            }
            __builtin_amdgcn_s_setprio(1);
#pragma unroll
            for (int m = 0; m < 4; m++)
#pragma unroll
                for (int n = 0; n < 2; n++)
                    acc[m][n] = __builtin_amdgcn_mfma_f32_16x16x32_bf16(
                        af[m], bfv[n], acc[m][n], 0, 0, 0);
            __builtin_amdgcn_s_setprio(0);
        }
        // phase ks=1 (no barrier: reads cur, writes went to nxt)
        {
            const int ch = ((4 | lg) ^ xk) * 8;
            bf16x8 af[4], bfv[2];
#pragma unroll
            for (int m = 0; m < 4; m++)
                af[m] = *(const bf16x8*)(Asg + (wr + m * 16 + la) * 64 + ch);
#pragma unroll
            for (int n = 0; n < 2; n++)
                bfv[n] = *(const bf16x8*)(Bsg + (wc + n * 16 + la) * 64 + ch);
            __builtin_amdgcn_s_setprio(1);
#pragma unroll
            for (int m = 0; m < 4; m++)
#pragma unroll
                for (int n = 0; n < 2; n++)
                    acc[m][n] = __builtin_amdgcn_mfma_f32_16x16x32_bf16(
                        af[m], bfv[n], acc[m][n], 0, 0, 0);
            __builtin_amdgcn_s_setprio(0);
        }
        __builtin_amdgcn_s_barrier();   // reads of cur done before overwrite
    }

    // ---- single-round combine: group 1 -> group 0 ----
    float* cbuf = (float*)smem;
    __syncthreads();
    if (g == 1) {
#pragma unroll
        for (int m = 0; m < 4; m++)
#pragma unroll
            for (int n = 0; n < 2; n++)
#pragma unroll
                for (int j = 0; j < 4; j++)
                    cbuf[(wr + m * 16 + lg * 4 + j) * 132 + wc + n * 16 + la] =
                        acc[m][n][j];
    }
    __syncthreads();
    if (g != 0) return;

#pragma unroll
    for (int m = 0; m < 4; m++)
#pragma unroll
        for (int n = 0; n < 2; n++)
#pragma unroll
            for (int j = 0; j < 4; j++) {
                int row = brow + wr + m * 16 + lg * 4 + j;
                int col = bcol + wc + n * 16 + la;
                float v = acc[m][n][j] +
                          cbuf[(wr + m * 16 + lg * 4 + j) * 132 + wc + n * 16 + la];
                if (EPI == 0) {
                    ((unsigned short*)C)[(size_t)row * N + col] = f2bf(v);
                } else if (EPI == 1) {
                    ((float*)C)[(size_t)row * N + col] =
                        v + bias[col] + res[(size_t)row * N + col];
                } else {
                    ((unsigned short*)C)[(size_t)row * N + col] =
                        f2bf(gelu_t(v + bias[col]));
                }
            }
}

// ---------------------------------------------------------------------------
// Causal flash attention, NO-MAX softmax, Ps stride 64, P write-early.
// Unpaired flat grid 1024 blocks, co-residency-balanced qt map; 8 waves
// (A=even / B=odd kv tiles); single-buffered gload_lds staging (48KB).
// ---------------------------------------------------------------------------
__global__ __launch_bounds__(512) void attn_kernel(
    const unsigned short* __restrict__ QKV,
    const unsigned short* __restrict__ Vt,
    unsigned short* __restrict__ ctx)
{
    __shared__ alignas(16) unsigned short KVs[2][8192];   // 32KB: [group] K|V
    __shared__ alignas(16) unsigned short Ps[8][16 * 64]; // 16KB
    float* obuf = (float*)&KVs[0][0];        // merge scratch (aliases KVs)
    float* mlbuf = obuf + 64 * 68;

    const int t = threadIdx.x, lane = t & 63, w = t >> 6;
    const int wg = w >> 2;
    const int wl = w & 3;
    const int la = lane & 15, lg = lane >> 4;
    const int id = blockIdx.x;
    const int c = id & 31;
    const int h = c >> 1, b = c & 1;
    const int r = id >> 5;
    const int j = r & 7, v = r >> 3;
    const int qt = (v == 0) ? j : (v == 1) ? (31 - j) : (v == 2) ? (8 + j) : (23 - j);
    const float C2 = 0.18033688011112042f;  // 0.125 * log2(e)

    const unsigned short* kg = QKV + (size_t)(b * 2048) * 3072 + 1024 + h * 64;
    const unsigned short* vg = Vt + (size_t)((b * 16 + h) * 64) * 2048;
    const int th = t & 255;
    const int sg = t >> 8;
    const int srow = th >> 3;
    const int sxcol = (((th & 7) ^ (srow & 7)) * 8);

    unsigned short* pw = (unsigned short*)Ps[w];
    const int xk = la & 7;

    const int qbase = qt * 64;
    const int qr = qbase + wl * 16 + la;

    const unsigned short* qp =
        QKV + (size_t)(b * 2048 + qbase + wl * 16 + la) * 3072 + h * 64;
    bf16x8 qf0 = *(const bf16x8*)(qp + lg * 8);
    bf16x8 qf1 = *(const bf16x8*)(qp + 32 + lg * 8);

    f32x4 o[4];
#pragma unroll
    for (int n = 0; n < 4; n++) o[n] = (f32x4){0.f, 0.f, 0.f, 0.f};
    float lrow = 0.f;

    const int nt = qt + 1;
    const int npair = (nt + 1) >> 1;

    for (int i = 0; i < npair; ++i) {
        __syncthreads();   // previous iter's reads done
        {   // stage pair i (tile 2i+sg) into the single KV buffer
            const int kv0 = (2 * i + sg) * 64;
            unsigned short* kd = KVs[sg];
            gload16(kg + (size_t)(kv0 + srow) * 3072 + sxcol, kd + th * 8);
            gload16(kg + (size_t)(kv0 + 32 + srow) * 3072 + sxcol, kd + 2048 + th * 8);
            gload16(vg + (size_t)srow * 2048 + kv0 + sxcol, kd + 4096 + th * 8);
            gload16(vg + (size_t)(32 + srow) * 2048 + kv0 + sxcol, kd + 6144 + th * 8);
        }
        __syncthreads();   // staged visible (barrier drains vmcnt)
        const int tile = 2 * i + wg;
        if (tile < nt) {
            const int kv = tile * 64;
            const unsigned short* Kc = KVs[wg];
            const unsigned short* Vc = Kc + 4096;

            f32x4 sa[4];
            __builtin_amdgcn_s_setprio(1);
#pragma unroll
            for (int n = 0; n < 4; n++) {
                f32x4 z = (f32x4){0.f, 0.f, 0.f, 0.f};
                const unsigned short* kr = Kc + (n * 16 + la) * 64;
                bf16x8 k0 = *(const bf16x8*)(kr + (lg ^ xk) * 8);
                bf16x8 k1 = *(const bf16x8*)(kr + ((4 | lg) ^ xk) * 8);
                z = __builtin_amdgcn_mfma_f32_16x16x32_bf16(k0, qf0, z, 0, 0, 0);
                z = __builtin_amdgcn_mfma_f32_16x16x32_bf16(k1, qf1, z, 0, 0, 0);
                sa[n] = z;
            }
            __builtin_amdgcn_s_setprio(0);
            if (tile == qt) {
#pragma unroll
                for (int n = 0; n < 4; n++)
#pragma unroll
                    for (int jj = 0; jj < 4; jj++) {
                        int kc = kv + n * 16 + lg * 4 + jj;
                        if (kc > qr) sa[n][jj] = -1e30f;
                    }
            }
            // exp2 first, then pack+write P (drains under the reduce), then sum
#pragma unroll
            for (int n = 0; n < 4; n++)
#pragma unroll
                for (int jj = 0; jj < 4; jj++)
                    sa[n][jj] = exp2f(sa[n][jj] * C2);
#pragma unroll
            for (int n = 0; n < 4; n++)
#pragma unroll
                for (int jp = 0; jp < 2; jp++) {
                    unsigned int pk;
                    asm("v_cvt_pk_bf16_f32 %0, %1, %2"
                        : "=v"(pk) : "v"(sa[n][2 * jp]), "v"(sa[n][2 * jp + 1]));
                    int col = 16 * n + lg * 4 + 2 * jp;
                    int idx = la * 64 + (((col >> 3) ^ xk) * 8) + (col & 7);
                    *(unsigned int*)(pw + idx) = pk;
                }
            float psum = 0.f;
#pragma unroll
            for (int n = 0; n < 4; n++)
#pragma unroll
                for (int jj = 0; jj < 4; jj++)
                    psum += sa[n][jj];
            psum += __shfl_xor(psum, 16, 64);
            psum += __shfl_xor(psum, 32, 64);
            lrow += psum;
            asm volatile("s_waitcnt lgkmcnt(0)" ::: "memory");
            __builtin_amdgcn_s_setprio(1);
#pragma unroll
            for (int kk = 0; kk < 2; kk++) {
                bf16x8 pa = *(const bf16x8*)(pw + la * 64 + (((kk * 4 + lg) ^ xk) * 8));
#pragma unroll
                for (int n = 0; n < 4; n++) {
                    bf16x8 vb = *(const bf16x8*)(
                        Vc + (n * 16 + la) * 64 + (((kk * 4 + lg) ^ xk) * 8));
                    o[n] = __builtin_amdgcn_mfma_f32_16x16x32_bf16(pa, vb, o[n], 0, 0, 0);
                }
            }
            __builtin_amdgcn_s_setprio(0);
        }
    }

    // ---- merge group B into group A: plain add (common m == 0) ----
    __syncthreads();
    if (wg == 1) {
#pragma unroll
        for (int n = 0; n < 4; n++)
#pragma unroll
            for (int jj = 0; jj < 4; jj++)
                obuf[(wl * 16 + lg * 4 + jj) * 68 + n * 16 + la] = o[n][jj];
        if (lg == 0) mlbuf[wl * 16 + la] = lrow;
    }
    __syncthreads();
    if (wg == 0) {
        float lb = mlbuf[wl * 16 + la];
        float linv = 1.0f / (lrow + lb);
        float invv[4];
#pragma unroll
        for (int jj = 0; jj < 4; jj++)
            invv[jj] = __shfl(linv, lg * 4 + jj, 64);
#pragma unroll
        for (int n = 0; n < 4; n++)
#pragma unroll
            for (int jj = 0; jj < 4; jj++) {
                float ov = o[n][jj] +
                           obuf[(wl * 16 + lg * 4 + jj) * 68 + n * 16 + la];
                int row = b * 2048 + qbase + wl * 16 + lg * 4 + jj;
                int col = h * 64 + n * 16 + la;
                ctx[(size_t)row * 1024 + col] = f2bf(ov * invv[jj]);
            }
    }
}

// ---------------------------------------------------------------------------
__global__ __launch_bounds__(256) void ln_kernel(
    const float* __restrict__ x, const float* __restrict__ scale,
    const float* __restrict__ shift, unsigned short* __restrict__ out)
{
    const int row = blockIdx.x, t = threadIdx.x;
    const int lane = t & 63, w = t >> 6;
    const float4 v = ((const float4*)(x + (size_t)row * 1024))[t];
    float s = v.x + v.y + v.z + v.w;
#pragma unroll
    for (int off = 1; off < 64; off <<= 1) s += __shfl_xor(s, off, 64);
    __shared__ float red[8];
    if (lane == 0) red[w] = s;
    __syncthreads();
    float mean = (red[0] + red[1] + red[2] + red[3]) * (1.0f / 1024.0f);
    float d0 = v.x - mean, d1 = v.y - mean, d2 = v.z - mean, d3 = v.w - mean;
    float q = d0 * d0 + d1 * d1 + d2 * d2 + d3 * d3;
#pragma unroll
    for (int off = 1; off < 64; off <<= 1) q += __shfl_xor(q, off, 64);
    if (lane == 0) red[4 + w] = q;
    __syncthreads();
    float var = (red[4] + red[5] + red[6] + red[7]) * (1.0f / 1023.0f);
    float rinv = rsqrtf(var + 1e-6f);
    const int c = t * 4;
    out[(size_t)row * 1024 + c + 0] = f2bf(scale[c + 0] * (d0 * rinv) + shift[c + 0]);
    out[(size_t)row * 1024 + c + 1] = f2bf(scale[c + 1] * (d1 * rinv) + shift[c + 1]);
    out[(size_t)row * 1024 + c + 2] = f2bf(scale[c + 2] * (d2 * rinv) + shift[c + 2]);
    out[(size_t)row * 1024 + c + 3] = f2bf(scale[c + 3] * (d3 * rinv) + shift[c + 3]);
}

// ---------------------------------------------------------------------------
// Fused weight transpose: all 6 W[K][N] f32 -> Wt[N][K] bf16 in ONE launch.
// ---------------------------------------------------------------------------
__global__ __launch_bounds__(256) void transpose_all(
    const float* __restrict__ Wq, const float* __restrict__ Wk,
    const float* __restrict__ Wv, const float* __restrict__ Wo,
    const float* __restrict__ W1, const float* __restrict__ W2,
    unsigned short* __restrict__ WqkvT, unsigned short* __restrict__ WoT,
    unsigned short* __restrict__ W1T, unsigned short* __restrict__ W2T)
{
    __shared__ float tile[32][33];
    const int id = blockIdx.x;
    const float* W;
    unsigned short* Wt;
    int K, N, nb, kb;
    if (id < 4096) {
        const int wsel = id >> 10, loc = id & 1023;
        K = 1024; N = 1024;
        nb = (loc & 31) * 32; kb = (loc >> 5) * 32;
        W = (wsel == 0) ? Wq : (wsel == 1) ? Wk : (wsel == 2) ? Wv : Wo;
        Wt = (wsel == 3) ? WoT : (WqkvT + (size_t)wsel * 1024 * 1024);
    } else if (id < 8192) {
        const int loc = id - 4096;
        K = 1024; N = 4096;
        nb = (loc & 127) * 32; kb = (loc >> 7) * 32;
        W = W1; Wt = W1T;
    } else {
        const int loc = id - 8192;
        K = 4096; N = 1024;
        nb = (loc & 31) * 32; kb = (loc >> 5) * 32;
        W = W2; Wt = W2T;
    }
    const int tx = threadIdx.x, ty = threadIdx.y;
#pragma unroll
    for (int j = 0; j < 4; j++)
        tile[ty + j * 8][tx] = W[(size_t)(kb + ty + j * 8) * N + nb + tx];
    __syncthreads();
#pragma unroll
    for (int j = 0; j < 4; j++)
        Wt[(size_t)(nb + ty + j * 8) * K + kb + tx] = f2bf(tile[tx][ty + j * 8]);
}

// ---------------------------------------------------------------------------
__global__ __launch_bounds__(256) void transpose_v(
    const unsigned short* __restrict__ QKV, unsigned short* __restrict__ Vt)
{
    __shared__ unsigned short tile[32][33];
    const int sb = blockIdx.x * 32, hb = blockIdx.y * 32;
    const int bh = blockIdx.z;
    const int b = bh >> 4, h = bh & 15;
    const int tx = threadIdx.x, ty = threadIdx.y;
    const unsigned short* src = QKV + (size_t)(b * 2048) * 3072 + 2048 + h * 64;
#pragma unroll
    for (int j = 0; j < 4; j++)
        tile[ty + j * 8][tx] = src[(size_t)(sb + ty + j * 8) * 3072 + hb + tx];
    __syncthreads();
    unsigned short* dst = Vt + (size_t)((b * 16 + h) * 64) * 2048;
#pragma unroll
    for (int j = 0; j < 4; j++)
        dst[(size_t)(hb + ty + j * 8) * 2048 + sb + tx] = tile[tx][ty + j * 8];
}

// ---------------------------------------------------------------------------
extern "C" void kernel_launch(void* const* d_in, const int* in_sizes, int n_in,
                              void* d_out, int out_size, void* d_ws, size_t ws_size,
                              hipStream_t stream)
{
    const float* x      = (const float*)d_in[0];
    const float* Wq     = (const float*)d_in[1];
    const float* Wk     = (const float*)d_in[2];
    const float* Wv     = (const float*)d_in[3];
    const float* Wo     = (const float*)d_in[4];
    const float* bo     = (const float*)d_in[5];
    const float* W1     = (const float*)d_in[6];
    const float* b1     = (const float*)d_in[7];
    const float* W2     = (const float*)d_in[8];
    const float* b2     = (const float*)d_in[9];
    const float* scale1 = (const float*)d_in[10];
    const float* shift1 = (const float*)d_in[11];
    const float* scale2 = (const float*)d_in[12];
    const float* shift2 = (const float*)d_in[13];
    float* out = (float*)d_out;

    char* ws = (char*)d_ws;
    unsigned short* xn    = (unsigned short*)(ws);                   // 8MB (also yn)
    unsigned short* QKV   = (unsigned short*)(ws + (8ull << 20));    // 24MB
    unsigned short* VtB   = (unsigned short*)(ws + (32ull << 20));   // 8MB
    unsigned short* ctx   = (unsigned short*)(ws + (40ull << 20));   // 8MB
    unsigned short* g     = (unsigned short*)(ws + (8ull << 20));    // 32MB (reuse QKV+Vt)
    unsigned short* WqkvT = (unsigned short*)(ws + (48ull << 20));   // 6MB
    unsigned short* WoT   = (unsigned short*)(ws + (54ull << 20));   // 2MB
    unsigned short* W1T   = (unsigned short*)(ws + (56ull << 20));   // 8MB
    unsigned short* W2T   = (unsigned short*)(ws + (64ull << 20));   // 8MB -> 72MB total
    float* h = out;  // h lives in d_out

    dim3 blk(256);
    dim3 tb(32, 8);

    transpose_all<<<dim3(12288), tb, 0, stream>>>(Wq, Wk, Wv, Wo, W1, W2,
                                                  WqkvT, WoT, W1T, W2T);

    ln_kernel<<<4096, blk, 0, stream>>>(x, scale1, shift1, xn);
    gemm_bt256<0, 192><<<dim3(16, 16), dim3(512), 0, stream>>>(
        xn, WqkvT, QKV, nullptr, 4096, 3072, 1024);
    transpose_v<<<dim3(64, 2, 32), tb, 0, stream>>>(QKV, VtB);
    attn_kernel<<<dim3(1024), dim3(512), 0, stream>>>(QKV, VtB, ctx);
    gemm_bt_ks2<1><<<dim3(32, 8), dim3(1024), 0, stream>>>(ctx, WoT, h, bo, x,
                                                           4096, 1024, 1024);
    ln_kernel<<<4096, blk, 0, stream>>>(h, scale2, shift2, xn);
    gemm_bt256<2, 256><<<dim3(16, 16), dim3(512), 0, stream>>>(
        xn, W1T, g, b1, 4096, 4096, 1024);
    gemm_bt_ks2<1><<<dim3(32, 8), dim3(1024), 0, stream>>>(g, W2T, out, b2, h,
                                                           4096, 1024, 4096);
}